// Round 3
// baseline (393.717 us; speedup 1.0000x reference)
//
#include <hip/hip_runtime.h>

// Linear state-space scan:  x_{k+1} = A x_k + B u_k ; outputs X_k (pre-step
// state) and y_k = C x_k + D u_k (normalized in, denormalized out).
// N=16384 steps, R=256 columns, NX=8, NU=NY=2.
//
// SINGLE-KERNEL flag-synced parallel scan (no grid.sync — measured ~120us/sync;
// fine-grained release/acquire flags cost ~1us/hop instead):
//   512 blocks x 256 thr, 2 blocks/CU -> ALL co-resident (spin-safe).
//   phase A : normalize u -> 64KB LDS (kept for replay; saves the 33.5MB
//             u re-read), zero-state d32 for own 32-step chunk.
//             non-combiners publish d32, release-add cnt[m].
//   combiner (c&7==7): acquire cnt[m] -> Horner_{A32}(7 slices + own) ->
//             d256[m], release-add DCNT; acquire DCNT==all ->
//             PARALLEL lookback: s256[m] = Horner_{A256}(d256[0..m-1]) from
//             x0 (bit-identical op sequence to the old serial phase2),
//             pipelined in 8-slice tiles; publish s256[m] + flag_s[m].
//   all     : acquire flag_s[m], advance p=c&7 fine chunks via d32,
//             replay 32 steps from LDS u, nt-store X and denorm Y.
// Sync correctness: plain data stores ordered by per-thread RELEASE
// fetch_add (waitcnt+wbl2); readers: thread-0 ACQUIRE load (buffer_inv of
// CU-L1 + XCD-L2) + __syncthreads fan-out. Release->acquire chains make
// d32 visible transitively through cnt->fs. Flags zeroed per-launch via
// hipMemsetAsync (ws may be poisoned between runs).

#define NSTEPS 16384
#define NUI 2
#define RB 256
#define NXS 8
#define NYO 2
#define LF 32
#define NC1 (NSTEPS / LF)   // 512 fine chunks (32 steps each)
#define NSUP 8              // fine chunks per super-chunk
#define NC2B (NC1 / NSUP)   // 64 super-chunks of 256 steps
#define CNT_TGT (7u * RB)   // 7 non-combiner blocks x 256 threads
#define DCNT_TGT ((unsigned)NC2B * RB)
#define FS_TGT ((unsigned)RB)

__device__ __forceinline__ void waitflag(unsigned int* f, unsigned int tgt) {
    if (threadIdx.x == 0) {
        while (__hip_atomic_load(f, __ATOMIC_RELAXED, __HIP_MEMORY_SCOPE_AGENT) < tgt)
            __builtin_amdgcn_s_sleep(2);
        (void)__hip_atomic_load(f, __ATOMIC_ACQUIRE, __HIP_MEMORY_SCOPE_AGENT);
    }
    __syncthreads();   // fan-out: block-uniform call sites only
}

__global__ __launch_bounds__(RB, 2) void fused_k(
    const float* __restrict__ u, const float* __restrict__ x0,
    const float* __restrict__ A, const float* __restrict__ Bu,
    const float* __restrict__ Cy, const float* __restrict__ Dyu,
    const float* __restrict__ um, const float* __restrict__ us,
    const float* __restrict__ ym, const float* __restrict__ ys,
    float* __restrict__ Y, float* __restrict__ X,
    float* __restrict__ d32, float* __restrict__ d256,
    float* __restrict__ s256, unsigned int* __restrict__ flags) {
    __shared__ float uL[LF][NUI][RB];   // 64 KB normalized u (this chunk)
    __shared__ float Ms[64];
    __shared__ float A32s[64];
    __shared__ float A256s[64];

    const int c = blockIdx.x;   // 0..511
    const int t = threadIdx.x;
    const int r = t;            // column
    const int m = c >> 3;       // super-chunk
    const int p = c & 7;        // position in super-chunk (block-uniform)
    unsigned int* cnt  = flags;             // [NC2B]
    unsigned int* dcnt = flags + NC2B;      // [1]
    unsigned int* fs   = flags + NC2B + 1;  // [NC2B]

    // ---- phase A: normalize u -> LDS, zero-state 32-step response ----
    float a[NXS][NXS];
    #pragma unroll
    for (int i = 0; i < NXS; ++i)
        #pragma unroll
        for (int j = 0; j < NXS; ++j) a[i][j] = A[i * NXS + j];
    float b0[NXS], b1[NXS];
    #pragma unroll
    for (int i = 0; i < NXS; ++i) { b0[i] = Bu[i * NUI]; b1[i] = Bu[i * NUI + 1]; }
    const float um0 = um[0], um1 = um[1];
    const float is0 = 1.0f / us[0], is1 = 1.0f / us[1];
    float tv[NXS];
    #pragma unroll
    for (int i = 0; i < NXS; ++i) tv[i] = 0.f;
    {
        const float* up = u + (size_t)c * LF * NUI * RB + r;
        #pragma unroll 4
        for (int j = 0; j < LF; ++j) {
            const float u0 = (up[0]  - um0) * is0;
            const float u1 = (up[RB] - um1) * is1;
            up += NUI * RB;
            uL[j][0][r] = u0;
            uL[j][1][r] = u1;
            float nt[NXS];
            #pragma unroll
            for (int i = 0; i < NXS; ++i) {
                float acc = fmaf(b0[i], u0, b1[i] * u1);
                #pragma unroll
                for (int k = 0; k < NXS; ++k) acc = fmaf(a[i][k], tv[k], acc);
                nt[i] = acc;
            }
            #pragma unroll
            for (int i = 0; i < NXS; ++i) tv[i] = nt[i];
        }
    }
    if (p != 7) {   // combiner's own slice is never read by others
        float* dp = d32 + (size_t)c * NXS * RB + r;
        #pragma unroll
        for (int i = 0; i < NXS; ++i) dp[i * RB] = tv[i];
        __hip_atomic_fetch_add(&cnt[m], 1u, __ATOMIC_RELEASE,
                               __HIP_MEMORY_SCOPE_AGENT);
    }

    // ---- A powers ladder (overlaps other blocks' phase A) ----
    if (t < 64) Ms[t] = A[t];
    __syncthreads();
    {
        const int pi = t >> 3, pj = t & 7;
        #pragma unroll
        for (int it = 0; it < 8; ++it) {   // A^2 .. A^256
            float acc = 0.f;
            if (t < 64) {
                #pragma unroll
                for (int k = 0; k < 8; ++k) acc += Ms[pi * 8 + k] * Ms[k * 8 + pj];
            }
            __syncthreads();
            if (t < 64) {
                Ms[t] = acc;
                if (it == 4) A32s[t] = acc;   // A^32
            }
            __syncthreads();
        }
        if (t < 64) A256s[t] = Ms[t];          // A^256
        __syncthreads();
    }

    float sb[NXS];   // start state of super-chunk m for this column

    if (p == 7) {
        // ---------------- combiner ----------------
        float xv[NXS];
        #pragma unroll
        for (int i = 0; i < NXS; ++i) xv[i] = x0[i * RB + r];

        waitflag(&cnt[m], CNT_TGT);
        {
            float a32[NXS][NXS];
            #pragma unroll
            for (int i = 0; i < NXS; ++i)
                #pragma unroll
                for (int j = 0; j < NXS; ++j) a32[i][j] = A32s[i * 8 + j];
            float xq[NSUP - 1][NXS];
            #pragma unroll
            for (int q = 0; q < NSUP - 1; ++q) {
                const float* dq = d32 + (size_t)(NSUP * m + q) * NXS * RB + r;
                #pragma unroll
                for (int i = 0; i < NXS; ++i) xq[q][i] = dq[i * RB];
            }
            float s[NXS];
            #pragma unroll
            for (int i = 0; i < NXS; ++i) s[i] = xq[0][i];
            #pragma unroll
            for (int q = 1; q < NSUP - 1; ++q) {
                float nt[NXS];
                #pragma unroll
                for (int i = 0; i < NXS; ++i) {
                    float acc = xq[q][i];
                    #pragma unroll
                    for (int k = 0; k < NXS; ++k) acc = fmaf(a32[i][k], s[k], acc);
                    nt[i] = acc;
                }
                #pragma unroll
                for (int i = 0; i < NXS; ++i) s[i] = nt[i];
            }
            {   // last term = own tv (in registers)
                float nt[NXS];
                #pragma unroll
                for (int i = 0; i < NXS; ++i) {
                    float acc = tv[i];
                    #pragma unroll
                    for (int k = 0; k < NXS; ++k) acc = fmaf(a32[i][k], s[k], acc);
                    nt[i] = acc;
                }
                #pragma unroll
                for (int i = 0; i < NXS; ++i) s[i] = nt[i];
            }
            float* o = d256 + (size_t)m * NXS * RB + r;
            #pragma unroll
            for (int i = 0; i < NXS; ++i) o[i * RB] = s[i];
        }
        __hip_atomic_fetch_add(dcnt, 1u, __ATOMIC_RELEASE,
                               __HIP_MEMORY_SCOPE_AGENT);

        // lookback: sb = Horner_{A256}(d256[0..m-1]) from x0
        #pragma unroll
        for (int i = 0; i < NXS; ++i) sb[i] = xv[i];
        if (m > 0) {
            waitflag(dcnt, DCNT_TGT);
            float a256[NXS][NXS];
            #pragma unroll
            for (int i = 0; i < NXS; ++i)
                #pragma unroll
                for (int j = 0; j < NXS; ++j) a256[i][j] = A256s[i * 8 + j];
            for (int base = 0; base < m; base += 8) {   // <=8 tiles
                float T[8][NXS];
                #pragma unroll
                for (int k = 0; k < 8; ++k) {
                    if (base + k < m) {
                        const float* dq = d256 + (size_t)(base + k) * NXS * RB + r;
                        #pragma unroll
                        for (int i = 0; i < NXS; ++i) T[k][i] = dq[i * RB];
                    }
                }
                #pragma unroll
                for (int k = 0; k < 8; ++k) {
                    if (base + k < m) {
                        float nt[NXS];
                        #pragma unroll
                        for (int i = 0; i < NXS; ++i) {
                            float acc = T[k][i];
                            #pragma unroll
                            for (int kk = 0; kk < NXS; ++kk)
                                acc = fmaf(a256[i][kk], sb[kk], acc);
                            nt[i] = acc;
                        }
                        #pragma unroll
                        for (int i = 0; i < NXS; ++i) sb[i] = nt[i];
                    }
                }
            }
        }
        {
            float* sp = s256 + (size_t)m * NXS * RB + r;
            #pragma unroll
            for (int i = 0; i < NXS; ++i) sp[i * RB] = sb[i];
        }
        __hip_atomic_fetch_add(&fs[m], 1u, __ATOMIC_RELEASE,
                               __HIP_MEMORY_SCOPE_AGENT);
    } else {
        // ---------------- consumer ----------------
        waitflag(&fs[m], FS_TGT);
        const float* sp = s256 + (size_t)m * NXS * RB + r;
        #pragma unroll
        for (int i = 0; i < NXS; ++i) sb[i] = sp[i * RB];
    }

    // ---- advance start by p fine chunks: sb = A32 sb + d32[8m+q] ----
    if (p) {
        float a32[NXS][NXS];
        #pragma unroll
        for (int i = 0; i < NXS; ++i)
            #pragma unroll
            for (int j = 0; j < NXS; ++j) a32[i][j] = A32s[i * 8 + j];
        float P[NSUP - 1][NXS];
        #pragma unroll
        for (int q = 0; q < NSUP - 1; ++q) {
            if (q < p) {
                const float* dq = d32 + (size_t)(NSUP * m + q) * NXS * RB + r;
                #pragma unroll
                for (int i = 0; i < NXS; ++i) P[q][i] = dq[i * RB];
            }
        }
        #pragma unroll
        for (int q = 0; q < NSUP - 1; ++q) {
            if (q < p) {
                float nt[NXS];
                #pragma unroll
                for (int i = 0; i < NXS; ++i) {
                    float acc = P[q][i];
                    #pragma unroll
                    for (int k = 0; k < NXS; ++k) acc = fmaf(a32[i][k], sb[k], acc);
                    nt[i] = acc;
                }
                #pragma unroll
                for (int i = 0; i < NXS; ++i) sb[i] = nt[i];
            }
        }
    }

    // ---- replay 32 steps from LDS u; nt-store X and denormalized Y ----
    float c0[NXS], c1[NXS];
    #pragma unroll
    for (int k = 0; k < NXS; ++k) { c0[k] = Cy[k]; c1[k] = Cy[NXS + k]; }
    const float d00 = Dyu[0], d01 = Dyu[1], d10 = Dyu[2], d11 = Dyu[3];
    const float ym0 = ym[0], ym1 = ym[1], ys0 = ys[0], ys1 = ys[1];
    float* Xp = X + (size_t)c * LF * NXS * RB + r;
    float* Yp = Y + (size_t)c * LF * NYO * RB + r;
    #pragma unroll 4
    for (int j = 0; j < LF; ++j) {
        const float u0 = uL[j][0][r];
        const float u1 = uL[j][1][r];
        #pragma unroll
        for (int i = 0; i < NXS; ++i)
            __builtin_nontemporal_store(sb[i], Xp + i * RB);
        Xp += NXS * RB;
        float y0 = fmaf(d00, u0, d01 * u1);
        float y1 = fmaf(d10, u0, d11 * u1);
        #pragma unroll
        for (int k = 0; k < NXS; ++k) {
            y0 = fmaf(c0[k], sb[k], y0);
            y1 = fmaf(c1[k], sb[k], y1);
        }
        __builtin_nontemporal_store(fmaf(y0, ys0, ym0), Yp);
        __builtin_nontemporal_store(fmaf(y1, ys1, ym1), Yp + RB);
        Yp += NYO * RB;
        float nt[NXS];
        #pragma unroll
        for (int i = 0; i < NXS; ++i) {
            float acc = fmaf(b0[i], u0, b1[i] * u1);
            #pragma unroll
            for (int k = 0; k < NXS; ++k) acc = fmaf(a[i][k], sb[k], acc);
            nt[i] = acc;
        }
        #pragma unroll
        for (int i = 0; i < NXS; ++i) sb[i] = nt[i];
    }
}

extern "C" void kernel_launch(void* const* d_in, const int* in_sizes, int n_in,
                              void* d_out, int out_size, void* d_ws, size_t ws_size,
                              hipStream_t stream) {
    const float* u   = (const float*)d_in[0];
    const float* x0  = (const float*)d_in[1];
    const float* A   = (const float*)d_in[2];
    const float* Bu  = (const float*)d_in[3];
    const float* Cy  = (const float*)d_in[4];
    const float* Dyu = (const float*)d_in[5];
    const float* um  = (const float*)d_in[6];
    const float* us  = (const float*)d_in[7];
    const float* ym  = (const float*)d_in[8];
    const float* ys  = (const float*)d_in[9];

    float* Y = (float*)d_out;                       // (N, NY, R)
    float* X = Y + (size_t)NSTEPS * NYO * RB;       // (N, NX, R)

    float* ws   = (float*)d_ws;
    float* d32  = ws;                               // NC1*NX*R  = 4 MB
    float* d256 = d32 + (size_t)NC1 * NXS * RB;     // NC2B*NX*R = 512 KB
    float* s256 = d256 + (size_t)NC2B * NXS * RB;   // NC2B*NX*R = 512 KB
    unsigned int* flags = (unsigned int*)(s256 + (size_t)NC2B * NXS * RB);

    // flags must be zero each run (ws may be poisoned between iterations)
    hipMemsetAsync(flags, 0, 1024, stream);
    fused_k<<<NC1, RB, 0, stream>>>(u, x0, A, Bu, Cy, Dyu, um, us, ym, ys,
                                    Y, X, d32, d256, s256, flags);
}